// Round 20
// baseline (285.249 us; speedup 1.0000x reference)
//
#include <hip/hip_runtime.h>
#include <hip/hip_bf16.h>

typedef __bf16 bf16x8 __attribute__((ext_vector_type(8)));
typedef float f32x4 __attribute__((ext_vector_type(4)));
typedef float f32x16 __attribute__((ext_vector_type(16)));
typedef unsigned short u16;

#define S_ 2048
#define D_ 2048
#define H_ 16
#define HD_ 128
#define SCALE_ 0.08838834764831845f   // 1/sqrt(128)

__device__ __forceinline__ u16 f2bf(float f) {
  unsigned u = __builtin_bit_cast(unsigned, f);
  u += 0x7fffu + ((u >> 16) & 1u);    // RNE
  return (u16)(u >> 16);
}

__device__ __forceinline__ void gload16(void* lds, const void* g) {
  __builtin_amdgcn_global_load_lds((const __attribute__((address_space(1))) void*)g,
                                   (__attribute__((address_space(3))) void*)lds, 16, 0, 0);
}

__device__ __forceinline__ f32x4 mfma16(bf16x8 a, bf16x8 b, f32x4 c) {
  return __builtin_amdgcn_mfma_f32_16x16x32_bf16(a, b, c, 0, 0, 0);
}
__device__ __forceinline__ f32x16 mfma32(bf16x8 a, bf16x8 b, f32x16 c) {
  return __builtin_amdgcn_mfma_f32_32x32x16_bf16(a, b, c, 0, 0, 0);
}

__device__ __forceinline__ unsigned cvt_pk_bf16(float lo, float hi) {
  unsigned r;
  asm("v_cvt_pk_bf16_f32 %0, %1, %2" : "=v"(r) : "v"(lo), "v"(hi));
  return r;
}

// ---------------- cast f32 -> bf16, vectorized ----------------
__global__ void k_cast_bf16(const float* __restrict__ in, u16* __restrict__ out, int n4) {
  int i = blockIdx.x * blockDim.x + threadIdx.x;
  if (i < n4) {
    float4 v = ((const float4*)in)[i];
    ushort4 o;
    o.x = f2bf(v.x); o.y = f2bf(v.y); o.z = f2bf(v.z); o.w = f2bf(v.w);
    ((ushort4*)out)[i] = o;
  }
}

// ------------- transpose + cast, float4-vectorized -------------
__global__ void k_transpose_cast(const float* __restrict__ in, u16* __restrict__ out,
                                 int rows, int cols) {
  __shared__ u16 tile[64][66];
  const int c0 = blockIdx.x * 64, r0 = blockIdx.y * 64;
  const int tx = threadIdx.x & 15, ty = threadIdx.x >> 4;
#pragma unroll
  for (int i = 0; i < 4; i++) {
    int r = ty + i * 16;
    float4 v = *(const float4*)&in[(long)(r0 + r) * cols + c0 + tx * 4];
    tile[r][tx * 4 + 0] = f2bf(v.x);
    tile[r][tx * 4 + 1] = f2bf(v.y);
    tile[r][tx * 4 + 2] = f2bf(v.z);
    tile[r][tx * 4 + 3] = f2bf(v.w);
  }
  __syncthreads();
#pragma unroll
  for (int i = 0; i < 4; i++) {
    int cc = ty + i * 16;
    ushort4 o;
    o.x = tile[tx * 4 + 0][cc];
    o.y = tile[tx * 4 + 1][cc];
    o.z = tile[tx * 4 + 2][cc];
    o.w = tile[tx * 4 + 3][cc];
    *(ushort4*)&out[(long)(c0 + cc) * rows + r0 + tx * 4] = o;
  }
}

// QKV scatter-store: Q -> qb[4096][2048]; K/V -> fragment-packed per-(bh,tile32) layouts
__device__ __forceinline__ void qkv_store(u16* __restrict__ qb, u16* __restrict__ kpk,
                                          u16* __restrict__ vpk, int row, int col, float val) {
  u16 o = f2bf(val);
  int h = col / 384;
  int m3 = col - h * 384;
  int b = row >> 11, s = row & 2047;
  int bh = b * 16 + h, t = s >> 5;
  if (m3 < 128) {
    qb[(long)row * 2048 + h * 128 + m3] = o;
  } else if (m3 < 256) {
    int dd = m3 - 128;
    long idx = ((((long)bh * 64 + t) * 8 + (dd >> 4)) * 64 + (((dd >> 3) & 1) << 5) + (s & 31)) * 8 + (dd & 7);
    kpk[idx] = o;
  } else {
    int dd = m3 - 256;
    long idx = ((((long)bh * 64 + t) * 8 + (((s >> 4) & 1) << 2) + (dd >> 5)) * 64 + (((s >> 3) & 1) << 5) + (dd & 31)) * 8 + (s & 7);
    vpk[idx] = o;
  }
}

// ------------- 8-phase-style 128x256 GEMM, counted vmcnt, exact-wave grids -------------
// BM=128 BN=256 BK=64, 512 thr = 8 waves (2M x 4N), per-wave 64x64, 4 phases/K-tile
// (Q0..Q3 = m-half x n-half, 8 MFMA each). LDS 128 KB: A 2x16KB, B 3x32KB (B staged
// 2 tiles ahead). Ledger: ph1 stages A(t+1); ph2/ph3 stage B(t+2) halves; ph4 waits
// vmcnt(4) = retires B(t+1)+A(t+1), leaves B(t+2)[4] in flight. Prologue A0,B0,B1 ->
// vmcnt(4). QKV grid 768 = 3.0 waves, dense 256 = 1.0 wave at 1 blk/CU (fixes R8's
// 1.5-wave quantization loss). Snake XCD block order (R16).
template <int MODE>   // 2: QKV fragment-scatter out; 0: f32 out
__global__ __launch_bounds__(512) void k_gemm8(const u16* __restrict__ A,
                                               const u16* __restrict__ Bt,
                                               const float* __restrict__ bias,
                                               void* __restrict__ Cv,
                                               int M, int N, int K, int NTM,
                                               u16* __restrict__ qb,
                                               u16* __restrict__ kpk,
                                               u16* __restrict__ vpk) {
  __shared__ __align__(16) u16 lA[2][128 * 64];
  __shared__ __align__(16) u16 lB[3][256 * 64];
  const int tid = threadIdx.x, w = tid >> 6, l = tid & 63;
  const int wm = w >> 2, wn = w & 3, lr = l & 15, lg = l >> 4;
  const int nwg = NTM * (N >> 8);
  const int per = nwg >> 3;                     // blocks per XCD chunk (nwg % 8 == 0)
  const int tnc = per / NTM;                    // tn columns per chunk
  const int xcd = (int)blockIdx.x & 7;
  const int local = (int)blockIdx.x >> 3;
  const int ss = local / (8 * tnc), rr = local % (8 * tnc);
  const int tm = (ss * 8 + (rr & 7)) << 7;
  const int tn = (xcd * tnc + (rr >> 3)) << 8;
  const int NT = K >> 6;

  f32x4 acc[4][4];
#pragma unroll
  for (int m = 0; m < 4; m++)
#pragma unroll
    for (int n = 0; n < 4; n++) acc[m][n] = {0.f, 0.f, 0.f, 0.f};

  // A tile 128x64 = 1024 chunks, 2 gload16/thread
  auto stageA = [&](int buf, int kt) {
#pragma unroll
    for (int i = 0; i < 2; i++) {
      int base = i * 512 + w * 64;
      int f = base + l, r = f >> 3, cg = (f & 7) ^ (r & 7);
      gload16(&lA[buf][base * 8], &A[(long)(tm + r) * K + kt * 64 + cg * 8]);
    }
  };
  // B half hf (128 rows) = 1024 chunks, 2 gload16/thread
  auto stageBh = [&](int buf, int kt, int hf) {
#pragma unroll
    for (int i = 0; i < 2; i++) {
      int base = i * 512 + w * 64;
      int f = base + l, r = f >> 3, cg = (f & 7) ^ (r & 7);
      gload16(&lB[buf][(hf * 1024 + base) * 8],
              &Bt[(long)(tn + hf * 128 + r) * K + kt * 64 + cg * 8]);
    }
  };

  // prologue: A0, B0, B1 ; retire A0+B0 -> vmcnt(4) leaves B1 in flight
  stageA(0, 0);
  stageBh(0, 0, 0); stageBh(0, 0, 1);
  if (NT > 1) { stageBh(1, 1, 0); stageBh(1, 1, 1); }
  asm volatile("s_waitcnt vmcnt(4)" ::: "memory");
  __builtin_amdgcn_s_barrier();

  for (int kt = 0; kt < NT; ++kt) {
    const int ba = kt & 1;
    const int bb = kt % 3;
    bf16x8 aL[2][2], aH[2][2], b01[2][2], b23[2][2];
    const int rowA = wm * 64;
    const int rowB = wn * 64;

    // ---- ph1: read aL(m01) + b01(n01); stage A(t+1); MFMA Q0 ----
#pragma unroll
    for (int m = 0; m < 2; m++)
#pragma unroll
      for (int k = 0; k < 2; k++) {
        int r = rowA + m * 16 + lr;
        aL[m][k] = *(const bf16x8*)&lA[ba][r * 64 + ((((k << 2) + lg) ^ (r & 7)) << 3)];
      }
#pragma unroll
    for (int n = 0; n < 2; n++)
#pragma unroll
      for (int k = 0; k < 2; k++) {
        int r = rowB + n * 16 + lr;
        b01[n][k] = *(const bf16x8*)&lB[bb][r * 64 + ((((k << 2) + lg) ^ (r & 7)) << 3)];
      }
    if (kt + 1 < NT) stageA(ba ^ 1, kt + 1);
    __builtin_amdgcn_s_barrier();
    asm volatile("s_waitcnt lgkmcnt(0)" ::: "memory");
    __builtin_amdgcn_sched_barrier(0);
    __builtin_amdgcn_s_setprio(1);
#pragma unroll
    for (int m = 0; m < 2; m++)
#pragma unroll
      for (int n = 0; n < 2; n++)
#pragma unroll
        for (int k = 0; k < 2; k++)
          acc[m][n] = mfma16(aL[m][k], b01[n][k], acc[m][n]);
    __builtin_amdgcn_s_setprio(0);
    __builtin_amdgcn_s_barrier();

    // ---- ph2: read b23(n23); stage B(t+2) h0; MFMA Q1 = (aL, b23) ----
#pragma unroll
    for (int n = 0; n < 2; n++)
#pragma unroll
      for (int k = 0; k < 2; k++) {
        int r = rowB + (n + 2) * 16 + lr;
        b23[n][k] = *(const bf16x8*)&lB[bb][r * 64 + ((((k << 2) + lg) ^ (r & 7)) << 3)];
      }
    if (kt + 2 < NT) stageBh((kt + 2) % 3, kt + 2, 0);
    __builtin_amdgcn_s_barrier();
    asm volatile("s_waitcnt lgkmcnt(0)" ::: "memory");
    __builtin_amdgcn_sched_barrier(0);
    __builtin_amdgcn_s_setprio(1);
#pragma unroll
    for (int m = 0; m < 2; m++)
#pragma unroll
      for (int n = 0; n < 2; n++)
#pragma unroll
        for (int k = 0; k < 2; k++)
          acc[m][n + 2] = mfma16(aL[m][k], b23[n][k], acc[m][n + 2]);
    __builtin_amdgcn_s_setprio(0);
    __builtin_amdgcn_s_barrier();

    // ---- ph3: read aH(m23); stage B(t+2) h1; MFMA Q2 = (aH, b01) ----
#pragma unroll
    for (int m = 0; m < 2; m++)
#pragma unroll
      for (int k = 0; k < 2; k++) {
        int r = rowA + (m + 2) * 16 + lr;
        aH[m][k] = *(const bf16x8*)&lA[ba][r * 64 + ((((k << 2) + lg) ^ (r & 7)) << 3)];
      }
    if (kt + 2 < NT) stageBh((kt + 2) % 3, kt + 2, 1);
    __builtin_amdgcn_s_barrier();
    asm volatile("s_waitcnt lgkmcnt(0)" ::: "memory");
    __builtin_amdgcn_sched_barrier(0);
    __builtin_amdgcn_s_setprio(1);
#pragma unroll
    for (int m = 0; m < 2; m++)
#pragma unroll
      for (int n = 0; n < 2; n++)
#pragma unroll
        for (int k = 0; k < 2; k++)
          acc[m + 2][n] = mfma16(aH[m][k], b01[n][k], acc[m + 2][n]);
    __builtin_amdgcn_s_setprio(0);
    __builtin_amdgcn_s_barrier();

    // ---- ph4: counted vmcnt; MFMA Q3 = (aH, b23) ----
    __builtin_amdgcn_s_barrier();
    if (kt + 2 < NT)
      asm volatile("s_waitcnt vmcnt(4)" ::: "memory");
    else
      asm volatile("s_waitcnt vmcnt(0)" ::: "memory");
    __builtin_amdgcn_sched_barrier(0);
    __builtin_amdgcn_s_setprio(1);
#pragma unroll
    for (int m = 0; m < 2; m++)
#pragma unroll
      for (int n = 0; n < 2; n++)
#pragma unroll
        for (int k = 0; k < 2; k++)
          acc[m + 2][n + 2] = mfma16(aH[m][k], b23[n][k], acc[m + 2][n + 2]);
    __builtin_amdgcn_s_setprio(0);
    __builtin_amdgcn_s_barrier();
  }

  // epilogue
#pragma unroll
  for (int n = 0; n < 4; n++) {
    int col = tn + wn * 64 + n * 16 + lr;
    float bv = bias[col];
#pragma unroll
    for (int m = 0; m < 4; m++) {
      int row0 = tm + wm * 64 + m * 16 + lg * 4;
#pragma unroll
      for (int j = 0; j < 4; j++) {
        float v = acc[m][n][j] + bv;
        if constexpr (MODE == 2)
          qkv_store(qb, kpk, vpk, row0 + j, col, v);
        else
          ((float*)Cv)[(long)(row0 + j) * N + col] = v;
      }
    }
  }
}

// ------------- causal flash attention: SPLIT-K across the 4 waves of a block -------------
__global__ __launch_bounds__(256, 2) void k_attn(const u16* __restrict__ qb,
                                                 const u16* __restrict__ kpk,
                                                 const u16* __restrict__ vpk,
                                                 const float* __restrict__ amask,
                                                 u16* __restrict__ ctx) {
  __shared__ float smO[4][64][65];
  __shared__ float smM[4][32], smL[4][32];
  const int bh = blockIdx.x, b = bh >> 4, h = bh & 15;
  const int tid = threadIdx.x, w = tid >> 6, l = tid & 63;
  const int lr5 = l & 31, hi = l >> 5;
  const int c = 63 - (int)blockIdx.y;         // LPT: heavy chunks dispatch first
  const int qrow0 = c << 5;
  const int nt = c + 1;

  const u16* kbase = kpk + (long)bh * 64 * 8 * 512 + l * 8;
  const u16* vbase = vpk + (long)bh * 64 * 8 * 512 + l * 8;
  const float* ab0 = amask + b * S_;

  bf16x8 qf[8];
  {
    const u16* qp = qb + (long)(b * S_ + qrow0 + lr5) * 2048 + h * HD_ + hi * 8;
#pragma unroll
    for (int ks = 0; ks < 8; ks++) qf[ks] = *(const bf16x8*)(qp + ks * 16);
  }

  f32x16 aO[4];
#pragma unroll
  for (int db = 0; db < 4; db++)
#pragma unroll
    for (int r = 0; r < 16; r++) aO[db][r] = 0.f;
  float mrun = -3.0e38f, lrun = 0.f;

  const int cnt = (w <= c) ? ((nt - w + 3) >> 2) : 0;   // my tile count

  bf16x8 kA[8], kB[8];
  if (cnt) {
    const u16* kp0 = kbase + (long)w * 4096;
#pragma unroll
    for (int f = 0; f < 8; f++) kA[f] = *(const bf16x8*)(kp0 + f * 512);
  }

  auto body = [&](bf16x8 (&cur)[8], bf16x8 (&nxt)[8], int t, bool pf) {
    const int t32 = t << 5;
    bf16x8 vf[8];
    {
      const u16* vp = vbase + (long)t * 4096;
#pragma unroll
      for (int f = 0; f < 8; f++) vf[f] = *(const bf16x8*)(vp + f * 512);
    }
    f32x4 am[4];
#pragma unroll
    for (int rg = 0; rg < 4; rg++) am[rg] = *(const f32x4*)(ab0 + t32 + rg * 8 + hi * 4);

    f32x16 aS;
#pragma unroll
    for (int r = 0; r < 16; r++) aS[r] = 0.f;
    __builtin_amdgcn_s_setprio(1);
#pragma unroll
    for (int ks = 0; ks < 8; ks++) aS = mfma32(cur[ks], qf[ks], aS);
    __builtin_amdgcn_s_setprio(0);

    if (pf) {
      const u16* kp = kbase + (long)(t + 4) * 4096;
#pragma unroll
      for (int f = 0; f < 8; f++) nxt[f] = *(const bf16x8*)(kp + f * 512);
    }

    float v[16];
    const bool needmask = (t == c);
#pragma unroll
    for (int rg = 0; rg < 4; rg++)
#pragma unroll
      for (int j = 0; j < 4; j++) {
        v[rg * 4 + j] = fmaf(aS[rg * 4 + j], SCALE_, am[rg][j]);
        if (needmask && (rg * 8 + hi * 4 + j > lr5)) v[rg * 4 + j] = -1e30f;
      }
    float mx = v[0];
#pragma unroll
    for (int i = 1; i < 16; i++) mx = fmaxf(mx, v[i]);
    mx = fmaxf(mx, __shfl_xor(mx, 32));

    if (!__all(mx <= mrun + 8.0f)) {          // defer-max (T13)
      float mnew = fmaxf(mrun, mx);
      float corr = __expf(mrun - mnew);
      lrun *= corr;
      mrun = mnew;
#pragma unroll
      for (int reg = 0; reg < 16; reg++) {
        float cb = __shfl(corr, (reg & 3) + 8 * (reg >> 2) + 4 * hi);
#pragma unroll
        for (int db = 0; db < 4; db++) aO[db][reg] *= cb;
      }
    }

    float ls = 0.f;
#pragma unroll
    for (int i = 0; i < 16; i++) { v[i] = __expf(v[i] - mrun); ls += v[i]; }
    ls += __shfl_xor(ls, 32);
    lrun += ls;

    unsigned pk[8];
#pragma unroll
    for (int q = 0; q < 8; q++) pk[q] = cvt_pk_bf16(v[2 * q], v[2 * q + 1]);
    bf16x8 pa[2];
#pragma unroll
    for (int kst = 0; kst < 2; kst++) {
      unsigned a0 = pk[4 * kst], a1 = pk[4 * kst + 1], a2 = pk[4 * kst + 2], a3 = pk[4 * kst + 3];
      unsigned s0 = hi ? a0 : a2;
      unsigned s1 = hi ? a1 : a3;
      unsigned r0 = __shfl_xor(s0, 32);
      unsigned r1 = __shfl_xor(s1, 32);
      union { unsigned u[4]; bf16x8 vv; } U;
      U.u[0] = hi ? r0 : a0;
      U.u[1] = hi ? r1 : a1;
      U.u[2] = hi ? a2 : r0;
      U.u[3] = hi ? a3 : r1;
      pa[kst] = U.vv;
    }

    __builtin_amdgcn_s_setprio(1);
#pragma unroll
    for (int kst = 0; kst < 2; kst++)
#pragma unroll
      for (int db = 0; db < 4; db++)
        aO[db] = mfma32(pa[kst], vf[kst * 4 + db], aO[db]);
    __builtin_amdgcn_s_setprio(0);
  };

  for (int i = 0; i < cnt; i += 2) {
    body(kA, kB, w + 4 * i, i + 1 < cnt);
    if (i + 1 < cnt) body(kB, kA, w + 4 * (i + 1), i + 2 < cnt);
  }

  // dump partials
#pragma unroll
  for (int db = 0; db < 4; db++)
#pragma unroll
    for (int reg = 0; reg < 16; reg++) smO[w][l][db * 16 + reg] = aO[db][reg];
  if (hi == 0) { smM[w][lr5] = mrun; smL[w][lr5] = lrun; }
  __syncthreads();

  // combine: wave w handles the db=w output quadrant
  {
    const int db = w;
#pragma unroll
    for (int reg = 0; reg < 16; reg++) {
      int r = (reg & 3) + 8 * (reg >> 2) + 4 * hi;
      float m0 = smM[0][r], m1 = smM[1][r], m2 = smM[2][r], m3 = smM[3][r];
      float ms = fmaxf(fmaxf(m0, m1), fmaxf(m2, m3));
      float f0 = __expf(m0 - ms), f1 = __expf(m1 - ms);
      float f2 = __expf(m2 - ms), f3 = __expf(m3 - ms);
      float lsum = smL[0][r] * f0 + smL[1][r] * f1 + smL[2][r] * f2 + smL[3][r] * f3;
      float val = smO[0][l][db * 16 + reg] * f0 + smO[1][l][db * 16 + reg] * f1 +
                  smO[2][l][db * 16 + reg] * f2 + smO[3][l][db * 16 + reg] * f3;
      int srow = qrow0 + r;
      ctx[(long)(b * S_ + srow) * D_ + h * HD_ + db * 32 + lr5] = f2bf(val / lsum);
    }
  }
}

extern "C" void kernel_launch(void* const* d_in, const int* in_sizes, int n_in,
                              void* d_out, int out_size, void* d_ws, size_t ws_size,
                              hipStream_t stream) {
  const float* x  = (const float*)d_in[0];
  const float* am = (const float*)d_in[1];
  const float* wq = (const float*)d_in[2];
  const float* bq = (const float*)d_in[3];
  const float* wd = (const float*)d_in[4];
  const float* bd = (const float*)d_in[5];
  float* out = (float*)d_out;
  char* ws = (char*)d_ws;

  // workspace layout (88 MB peak, overlaid):
  const size_t MB = 1048576;
  u16* xb   = (u16*)(ws);                  // [4096][2048] bf16 @0   (cast -> QKV GEMM)
  u16* wqT  = (u16*)(ws + 16 * MB);        // [6144][2048] bf16 @16  (-> QKV GEMM)
  u16* qb   = (u16*)(ws + 40 * MB);        // [4096][2048] bf16 @40  (GEMM -> attn)
  u16* kpk  = (u16*)(ws + 56 * MB);        // packed K @56           (GEMM -> attn)
  u16* vpk  = (u16*)(ws + 72 * MB);        // packed V @72           (GEMM -> attn)
  u16* ctxb = (u16*)(ws);                  // [4096][2048] bf16 @0   (attn -> dense; xb dead)
  u16* wdT  = (u16*)(ws + 16 * MB);        // [2048][2048] bf16 @16  (wqT dead)

  k_cast_bf16<<<8192, 256, 0, stream>>>(x, xb, 2097152);
  k_transpose_cast<<<dim3(96, 32), 256, 0, stream>>>(wq, wqT, 2048, 6144);
  k_gemm8<2><<<768, 512, 0, stream>>>(xb, wqT, bq, nullptr, 4096, 6144, 2048, 32, qb, kpk, vpk);
  k_transpose_cast<<<dim3(32, 32), 256, 0, stream>>>(wd, wdT, 2048, 2048);
  k_attn<<<dim3(32, 64), 256, 0, stream>>>(qb, kpk, vpk, am, ctxb);
  k_gemm8<0><<<256, 512, 0, stream>>>(ctxb, wdT, bd, out, 4096, 2048, 2048, 32,
                                      nullptr, nullptr, nullptr);
}

// Round 21
// 255.785 us; speedup vs baseline: 1.1152x; 1.1152x over previous
//
#include <hip/hip_runtime.h>
#include <hip/hip_bf16.h>

typedef __bf16 bf16x8 __attribute__((ext_vector_type(8)));
typedef float f32x4 __attribute__((ext_vector_type(4)));
typedef float f32x16 __attribute__((ext_vector_type(16)));
typedef unsigned short u16;

#define S_ 2048
#define D_ 2048
#define H_ 16
#define HD_ 128
#define SCALE_ 0.08838834764831845f   // 1/sqrt(128)

__device__ __forceinline__ u16 f2bf(float f) {
  unsigned u = __builtin_bit_cast(unsigned, f);
  u += 0x7fffu + ((u >> 16) & 1u);    // RNE
  return (u16)(u >> 16);
}

__device__ __forceinline__ void gload16(void* lds, const void* g) {
  __builtin_amdgcn_global_load_lds((const __attribute__((address_space(1))) void*)g,
                                   (__attribute__((address_space(3))) void*)lds, 16, 0, 0);
}

__device__ __forceinline__ f32x4 mfma16(bf16x8 a, bf16x8 b, f32x4 c) {
  return __builtin_amdgcn_mfma_f32_16x16x32_bf16(a, b, c, 0, 0, 0);
}
__device__ __forceinline__ f32x16 mfma32(bf16x8 a, bf16x8 b, f32x16 c) {
  return __builtin_amdgcn_mfma_f32_32x32x16_bf16(a, b, c, 0, 0, 0);
}

__device__ __forceinline__ unsigned cvt_pk_bf16(float lo, float hi) {
  unsigned r;
  asm("v_cvt_pk_bf16_f32 %0, %1, %2" : "=v"(r) : "v"(lo), "v"(hi));
  return r;
}

// ---------------- cast f32 -> bf16, vectorized ----------------
__global__ void k_cast_bf16(const float* __restrict__ in, u16* __restrict__ out, int n4) {
  int i = blockIdx.x * blockDim.x + threadIdx.x;
  if (i < n4) {
    float4 v = ((const float4*)in)[i];
    ushort4 o;
    o.x = f2bf(v.x); o.y = f2bf(v.y); o.z = f2bf(v.z); o.w = f2bf(v.w);
    ((ushort4*)out)[i] = o;
  }
}

// ------------- transpose + cast, float4-vectorized -------------
__global__ void k_transpose_cast(const float* __restrict__ in, u16* __restrict__ out,
                                 int rows, int cols) {
  __shared__ u16 tile[64][66];
  const int c0 = blockIdx.x * 64, r0 = blockIdx.y * 64;
  const int tx = threadIdx.x & 15, ty = threadIdx.x >> 4;
#pragma unroll
  for (int i = 0; i < 4; i++) {
    int r = ty + i * 16;
    float4 v = *(const float4*)&in[(long)(r0 + r) * cols + c0 + tx * 4];
    tile[r][tx * 4 + 0] = f2bf(v.x);
    tile[r][tx * 4 + 1] = f2bf(v.y);
    tile[r][tx * 4 + 2] = f2bf(v.z);
    tile[r][tx * 4 + 3] = f2bf(v.w);
  }
  __syncthreads();
#pragma unroll
  for (int i = 0; i < 4; i++) {
    int cc = ty + i * 16;
    ushort4 o;
    o.x = tile[tx * 4 + 0][cc];
    o.y = tile[tx * 4 + 1][cc];
    o.z = tile[tx * 4 + 2][cc];
    o.w = tile[tx * 4 + 3][cc];
    *(ushort4*)&out[(long)(c0 + cc) * rows + r0 + tx * 4] = o;
  }
}

// QKV scatter-store: Q -> qb[4096][2048]; K/V -> fragment-packed per-(bh,tile32) layouts
__device__ __forceinline__ void qkv_store(u16* __restrict__ qb, u16* __restrict__ kpk,
                                          u16* __restrict__ vpk, int row, int col, float val) {
  u16 o = f2bf(val);
  int h = col / 384;
  int m3 = col - h * 384;
  int b = row >> 11, s = row & 2047;
  int bh = b * 16 + h, t = s >> 5;
  if (m3 < 128) {
    qb[(long)row * 2048 + h * 128 + m3] = o;
  } else if (m3 < 256) {
    int dd = m3 - 128;
    long idx = ((((long)bh * 64 + t) * 8 + (dd >> 4)) * 64 + (((dd >> 3) & 1) << 5) + (s & 31)) * 8 + (dd & 7);
    kpk[idx] = o;
  } else {
    int dd = m3 - 256;
    long idx = ((((long)bh * 64 + t) * 8 + (((s >> 4) & 1) << 2) + (dd >> 5)) * 64 + (((s >> 3) & 1) << 5) + (dd & 31)) * 8 + (s & 7);
    vpk[idx] = o;
  }
}

// ------------- 128x128-tile 2-phase pipelined GEMM, 3-deep B prefetch -------------
// 256 thr = 4 waves (2m x 2n). LDS 80 KB (A 2x16KB + B 3x16KB) -> 2 blocks/CU.
// Structural rule (R8/R20): 2x256-thr blocks/CU (two independent barrier domains)
// beats any 512-thr single-block schedule on this chip. Snake XCD block order (R16:
// FETCH 209->135 MB). Counted vmcnt(8): B staged 2 K-tiles ahead, A 2 ahead.
template <int MODE>   // 2: QKV fragment-scatter out; 0: f32 out
__global__ __launch_bounds__(256, 2) void k_gemm(const u16* __restrict__ A,
                                                 const u16* __restrict__ Bt,
                                                 const float* __restrict__ bias,
                                                 void* __restrict__ Cv,
                                                 int M, int N, int K, int NTM,
                                                 u16* __restrict__ qb,
                                                 u16* __restrict__ kpk,
                                                 u16* __restrict__ vpk) {
  __shared__ __align__(16) u16 lA[2][128 * 64];
  __shared__ __align__(16) u16 lB[3][128 * 64];
  const int tid = threadIdx.x, w = tid >> 6, l = tid & 63;
  const int wm = w >> 1, wn = w & 1, lr = l & 15, lg = l >> 4;
  const int nwg = NTM * (N >> 7);
  const int per = nwg >> 3;                     // blocks per XCD chunk (nwg % 8 == 0)
  const int tnc = per / NTM;                    // tn columns per chunk
  const int xcd = (int)blockIdx.x & 7;
  const int local = (int)blockIdx.x >> 3;       // [0, per)
  const int ss = local / (8 * tnc), rr = local % (8 * tnc);
  const int tm = (ss * 8 + (rr & 7)) << 7;
  const int tn = (xcd * tnc + (rr >> 3)) << 7;
  const int NT = K >> 6;

  f32x4 acc[4][4];
#pragma unroll
  for (int m = 0; m < 4; m++)
#pragma unroll
    for (int n = 0; n < 4; n++) acc[m][n] = {0.f, 0.f, 0.f, 0.f};

  auto stageA = [&](int buf, int kt) {
#pragma unroll
    for (int i = 0; i < 4; i++) {
      int base = i * 256 + w * 64;
      int f = base + l, r = f >> 3, cg = (f & 7) ^ (r & 7);
      gload16(&lA[buf][base * 8], &A[(long)(tm + r) * K + kt * 64 + cg * 8]);
    }
  };
  auto stageB = [&](int buf, int kt) {
#pragma unroll
    for (int i = 0; i < 4; i++) {
      int base = i * 256 + w * 64;
      int f = base + l, r = f >> 3, cg = (f & 7) ^ (r & 7);
      gload16(&lB[buf][base * 8], &Bt[(long)(tn + r) * K + kt * 64 + cg * 8]);
    }
  };

  // prologue: A0,B0 ; A1,B1 ; retire tile0 (leave A1,B1 in flight)
  stageA(0, 0);
  stageB(0, 0);
  if (NT > 1) { stageA(1, 1); stageB(1, 1); }
  asm volatile("s_waitcnt vmcnt(8)" ::: "memory");
  __builtin_amdgcn_s_barrier();

  for (int kt = 0; kt < NT; ++kt) {
    const int ba = kt & 1;
    const int bb = kt % 3;
    bf16x8 af[4][2], bfr[2][2];
    // ---- phase 1: all A-frags + B n-frags 0,1 ; stage B(t+2) ----
#pragma unroll
    for (int m = 0; m < 4; m++)
#pragma unroll
      for (int k = 0; k < 2; k++) {
        int r = wm * 64 + m * 16 + lr;
        af[m][k] = *(const bf16x8*)&lA[ba][r * 64 + ((((k << 2) + lg) ^ (r & 7)) << 3)];
      }
#pragma unroll
    for (int n = 0; n < 2; n++)
#pragma unroll
      for (int k = 0; k < 2; k++) {
        int r = wn * 64 + n * 16 + lr;
        bfr[n][k] = *(const bf16x8*)&lB[bb][r * 64 + ((((k << 2) + lg) ^ (r & 7)) << 3)];
      }
    if (kt + 2 < NT) stageB((kt + 2) % 3, kt + 2);
    __builtin_amdgcn_s_barrier();
    asm volatile("s_waitcnt lgkmcnt(0)" ::: "memory");
    __builtin_amdgcn_sched_barrier(0);
    __builtin_amdgcn_s_setprio(1);
#pragma unroll
    for (int m = 0; m < 4; m++)
#pragma unroll
      for (int n = 0; n < 2; n++)
#pragma unroll
        for (int k = 0; k < 2; k++)
          acc[m][n] = mfma16(af[m][k], bfr[n][k], acc[m][n]);
    __builtin_amdgcn_s_setprio(0);
    __builtin_amdgcn_s_barrier();

    // ---- phase 2: B n-frags 2,3 ; stage A(t+2) into dead A region ----
#pragma unroll
    for (int n = 0; n < 2; n++)
#pragma unroll
      for (int k = 0; k < 2; k++) {
        int r = wn * 64 + (n + 2) * 16 + lr;
        bfr[n][k] = *(const bf16x8*)&lB[bb][r * 64 + ((((k << 2) + lg) ^ (r & 7)) << 3)];
      }
    if (kt + 2 < NT) stageA(ba, kt + 2);
    __builtin_amdgcn_s_barrier();
    if (kt + 2 < NT)
      asm volatile("s_waitcnt vmcnt(8) lgkmcnt(0)" ::: "memory");
    else
      asm volatile("s_waitcnt vmcnt(0) lgkmcnt(0)" ::: "memory");
    __builtin_amdgcn_sched_barrier(0);
    __builtin_amdgcn_s_setprio(1);
#pragma unroll
    for (int m = 0; m < 4; m++)
#pragma unroll
      for (int n = 0; n < 2; n++)
#pragma unroll
        for (int k = 0; k < 2; k++)
          acc[m][n + 2] = mfma16(af[m][k], bfr[n][k], acc[m][n + 2]);
    __builtin_amdgcn_s_setprio(0);
    __builtin_amdgcn_s_barrier();
  }

#pragma unroll
  for (int n = 0; n < 4; n++) {
    int col = tn + wn * 64 + n * 16 + lr;
    float bv = bias[col];
#pragma unroll
    for (int m = 0; m < 4; m++) {
      int row0 = tm + wm * 64 + m * 16 + lg * 4;
#pragma unroll
      for (int j = 0; j < 4; j++) {
        float v = acc[m][n][j] + bv;
        if constexpr (MODE == 2)
          qkv_store(qb, kpk, vpk, row0 + j, col, v);
        else
          ((float*)Cv)[(long)(row0 + j) * N + col] = v;
      }
    }
  }
}

// ------------- causal flash attention: SPLIT-K across the 4 waves of a block -------------
__global__ __launch_bounds__(256, 2) void k_attn(const u16* __restrict__ qb,
                                                 const u16* __restrict__ kpk,
                                                 const u16* __restrict__ vpk,
                                                 const float* __restrict__ amask,
                                                 u16* __restrict__ ctx) {
  __shared__ float smO[4][64][65];
  __shared__ float smM[4][32], smL[4][32];
  const int bh = blockIdx.x, b = bh >> 4, h = bh & 15;
  const int tid = threadIdx.x, w = tid >> 6, l = tid & 63;
  const int lr5 = l & 31, hi = l >> 5;
  const int c = 63 - (int)blockIdx.y;         // LPT: heavy chunks dispatch first
  const int qrow0 = c << 5;
  const int nt = c + 1;

  const u16* kbase = kpk + (long)bh * 64 * 8 * 512 + l * 8;
  const u16* vbase = vpk + (long)bh * 64 * 8 * 512 + l * 8;
  const float* ab0 = amask + b * S_;

  bf16x8 qf[8];
  {
    const u16* qp = qb + (long)(b * S_ + qrow0 + lr5) * 2048 + h * HD_ + hi * 8;
#pragma unroll
    for (int ks = 0; ks < 8; ks++) qf[ks] = *(const bf16x8*)(qp + ks * 16);
  }

  f32x16 aO[4];
#pragma unroll
  for (int db = 0; db < 4; db++)
#pragma unroll
    for (int r = 0; r < 16; r++) aO[db][r] = 0.f;
  float mrun = -3.0e38f, lrun = 0.f;

  const int cnt = (w <= c) ? ((nt - w + 3) >> 2) : 0;   // my tile count

  bf16x8 kA[8], kB[8];
  if (cnt) {
    const u16* kp0 = kbase + (long)w * 4096;
#pragma unroll
    for (int f = 0; f < 8; f++) kA[f] = *(const bf16x8*)(kp0 + f * 512);
  }

  auto body = [&](bf16x8 (&cur)[8], bf16x8 (&nxt)[8], int t, bool pf) {
    const int t32 = t << 5;
    bf16x8 vf[8];
    {
      const u16* vp = vbase + (long)t * 4096;
#pragma unroll
      for (int f = 0; f < 8; f++) vf[f] = *(const bf16x8*)(vp + f * 512);
    }
    f32x4 am[4];
#pragma unroll
    for (int rg = 0; rg < 4; rg++) am[rg] = *(const f32x4*)(ab0 + t32 + rg * 8 + hi * 4);

    f32x16 aS;
#pragma unroll
    for (int r = 0; r < 16; r++) aS[r] = 0.f;
    __builtin_amdgcn_s_setprio(1);
#pragma unroll
    for (int ks = 0; ks < 8; ks++) aS = mfma32(cur[ks], qf[ks], aS);
    __builtin_amdgcn_s_setprio(0);

    if (pf) {
      const u16* kp = kbase + (long)(t + 4) * 4096;
#pragma unroll
      for (int f = 0; f < 8; f++) nxt[f] = *(const bf16x8*)(kp + f * 512);
    }

    float v[16];
    const bool needmask = (t == c);
#pragma unroll
    for (int rg = 0; rg < 4; rg++)
#pragma unroll
      for (int j = 0; j < 4; j++) {
        v[rg * 4 + j] = fmaf(aS[rg * 4 + j], SCALE_, am[rg][j]);
        if (needmask && (rg * 8 + hi * 4 + j > lr5)) v[rg * 4 + j] = -1e30f;
      }
    float mx = v[0];
#pragma unroll
    for (int i = 1; i < 16; i++) mx = fmaxf(mx, v[i]);
    mx = fmaxf(mx, __shfl_xor(mx, 32));

    if (!__all(mx <= mrun + 8.0f)) {          // defer-max (T13)
      float mnew = fmaxf(mrun, mx);
      float corr = __expf(mrun - mnew);
      lrun *= corr;
      mrun = mnew;
#pragma unroll
      for (int reg = 0; reg < 16; reg++) {
        float cb = __shfl(corr, (reg & 3) + 8 * (reg >> 2) + 4 * hi);
#pragma unroll
        for (int db = 0; db < 4; db++) aO[db][reg] *= cb;
      }
    }

    float ls = 0.f;
#pragma unroll
    for (int i = 0; i < 16; i++) { v[i] = __expf(v[i] - mrun); ls += v[i]; }
    ls += __shfl_xor(ls, 32);
    lrun += ls;

    unsigned pk[8];
#pragma unroll
    for (int q = 0; q < 8; q++) pk[q] = cvt_pk_bf16(v[2 * q], v[2 * q + 1]);
    bf16x8 pa[2];
#pragma unroll
    for (int kst = 0; kst < 2; kst++) {
      unsigned a0 = pk[4 * kst], a1 = pk[4 * kst + 1], a2 = pk[4 * kst + 2], a3 = pk[4 * kst + 3];
      unsigned s0 = hi ? a0 : a2;
      unsigned s1 = hi ? a1 : a3;
      unsigned r0 = __shfl_xor(s0, 32);
      unsigned r1 = __shfl_xor(s1, 32);
      union { unsigned u[4]; bf16x8 vv; } U;
      U.u[0] = hi ? r0 : a0;
      U.u[1] = hi ? r1 : a1;
      U.u[2] = hi ? a2 : r0;
      U.u[3] = hi ? a3 : r1;
      pa[kst] = U.vv;
    }

    __builtin_amdgcn_s_setprio(1);
#pragma unroll
    for (int kst = 0; kst < 2; kst++)
#pragma unroll
      for (int db = 0; db < 4; db++)
        aO[db] = mfma32(pa[kst], vf[kst * 4 + db], aO[db]);
    __builtin_amdgcn_s_setprio(0);
  };

  for (int i = 0; i < cnt; i += 2) {
    body(kA, kB, w + 4 * i, i + 1 < cnt);
    if (i + 1 < cnt) body(kB, kA, w + 4 * (i + 1), i + 2 < cnt);
  }

  // dump partials
#pragma unroll
  for (int db = 0; db < 4; db++)
#pragma unroll
    for (int reg = 0; reg < 16; reg++) smO[w][l][db * 16 + reg] = aO[db][reg];
  if (hi == 0) { smM[w][lr5] = mrun; smL[w][lr5] = lrun; }
  __syncthreads();

  // combine: wave w handles the db=w output quadrant
  {
    const int db = w;
#pragma unroll
    for (int reg = 0; reg < 16; reg++) {
      int r = (reg & 3) + 8 * (reg >> 2) + 4 * hi;
      float m0 = smM[0][r], m1 = smM[1][r], m2 = smM[2][r], m3 = smM[3][r];
      float ms = fmaxf(fmaxf(m0, m1), fmaxf(m2, m3));
      float f0 = __expf(m0 - ms), f1 = __expf(m1 - ms);
      float f2 = __expf(m2 - ms), f3 = __expf(m3 - ms);
      float lsum = smL[0][r] * f0 + smL[1][r] * f1 + smL[2][r] * f2 + smL[3][r] * f3;
      float val = smO[0][l][db * 16 + reg] * f0 + smO[1][l][db * 16 + reg] * f1 +
                  smO[2][l][db * 16 + reg] * f2 + smO[3][l][db * 16 + reg] * f3;
      int srow = qrow0 + r;
      ctx[(long)(b * S_ + srow) * D_ + h * HD_ + db * 32 + lr5] = f2bf(val / lsum);
    }
  }
}

extern "C" void kernel_launch(void* const* d_in, const int* in_sizes, int n_in,
                              void* d_out, int out_size, void* d_ws, size_t ws_size,
                              hipStream_t stream) {
  const float* x  = (const float*)d_in[0];
  const float* am = (const float*)d_in[1];
  const float* wq = (const float*)d_in[2];
  const float* bq = (const float*)d_in[3];
  const float* wd = (const float*)d_in[4];
  const float* bd = (const float*)d_in[5];
  float* out = (float*)d_out;
  char* ws = (char*)d_ws;

  // workspace layout (88 MB peak, overlaid):
  const size_t MB = 1048576;
  u16* xb   = (u16*)(ws);                  // [4096][2048] bf16 @0   (cast -> QKV GEMM)
  u16* wqT  = (u16*)(ws + 16 * MB);        // [6144][2048] bf16 @16  (-> QKV GEMM)
  u16* qb   = (u16*)(ws + 40 * MB);        // [4096][2048] bf16 @40  (GEMM -> attn)
  u16* kpk  = (u16*)(ws + 56 * MB);        // packed K @56           (GEMM -> attn)
  u16* vpk  = (u16*)(ws + 72 * MB);        // packed V @72           (GEMM -> attn)
  u16* ctxb = (u16*)(ws);                  // [4096][2048] bf16 @0   (attn -> dense; xb dead)
  u16* wdT  = (u16*)(ws + 16 * MB);        // [2048][2048] bf16 @16  (wqT dead)

  k_cast_bf16<<<8192, 256, 0, stream>>>(x, xb, 2097152);
  k_transpose_cast<<<dim3(96, 32), 256, 0, stream>>>(wq, wqT, 2048, 6144);
  k_gemm<2><<<1536, 256, 0, stream>>>(xb, wqT, bq, nullptr, 4096, 6144, 2048, 32, qb, kpk, vpk);
  k_transpose_cast<<<dim3(32, 32), 256, 0, stream>>>(wd, wdT, 2048, 2048);
  k_attn<<<dim3(32, 64), 256, 0, stream>>>(qb, kpk, vpk, am, ctxb);
  k_gemm<0><<<512, 256, 0, stream>>>(ctxb, wdT, bd, out, 4096, 2048, 2048, 32,
                                     nullptr, nullptr, nullptr);
}